// Round 2
// baseline (935.659 us; speedup 1.0000x reference)
//
#include <hip/hip_runtime.h>
#include <hip/hip_bf16.h>
#include <stdint.h>

#define DDIM 512
#define NHEAD 8
#define BATCH 4
#define LTOK 24576
#define MROWS 98304          // BATCH * LTOK
#define MBLK 768             // MROWS / 128
#define MBLK_B 192           // blocks per batch
#define PTILE 4160           // 64*64 kv + 64 ksum (bf16 elements)

typedef __attribute__((ext_vector_type(8))) short short8;
typedef __attribute__((ext_vector_type(4))) float f32x4;

__device__ __forceinline__ float bf2f(unsigned short u) {
  union { unsigned int i; float f; } c; c.i = ((unsigned int)u) << 16; return c.f;
}
__device__ __forceinline__ unsigned short f2bf(float f) {
  union { float f; unsigned int i; } c; c.f = f;
  unsigned int r = c.i + 0x7FFFu + ((c.i >> 16) & 1u);
  return (unsigned short)(r >> 16);
}
__device__ __forceinline__ void gload16(const void* g, void* l) {
  __builtin_amdgcn_global_load_lds((const __attribute__((address_space(1))) void*)g,
                                   (__attribute__((address_space(3))) void*)l, 16, 0, 0);
}
__device__ __forceinline__ float elu1(float v) { return (v > 0.f) ? (v + 1.f) : __expf(v); }

// ---------------- weight prep: fused QKV weights (head-interleaved) + Wo + fused bias ----------------
// wf feature order: f<1024: head h=f>>7, (f>>6)&1 ? v : k, d=f&63 ; f>=1024: q[f-1024]
__global__ __launch_bounds__(256) void wprep(const float* __restrict__ Wq, const float* __restrict__ bq,
                                             const float* __restrict__ Wk, const float* __restrict__ bk,
                                             const float* __restrict__ Wv, const float* __restrict__ bv,
                                             const float* __restrict__ Wo,
                                             unsigned short* __restrict__ wf,
                                             unsigned short* __restrict__ wob,
                                             float* __restrict__ biasf) {
  long t = (long)blockIdx.x * 256 + threadIdx.x;
  if (t < 786432) {                       // 1536*512
    int f = (int)(t >> 9), c = (int)(t & 511);
    const float* src;
    if (f < 1024) { int hh = f >> 7, kv = (f >> 6) & 1, d = f & 63;
                    src = (kv ? Wv : Wk) + (long)(hh * 64 + d) * 512; }
    else          src = Wq + (long)(f - 1024) * 512;
    wf[t] = f2bf(src[c]);
  } else if (t < 786432 + 262144) {
    long i = t - 786432; wob[i] = f2bf(Wo[i]);
  } else if (t < 786432 + 262144 + 1536) {
    int f = (int)(t - (786432 + 262144));
    float v;
    if (f < 1024) { int hh = f >> 7, kv = (f >> 6) & 1, d = f & 63; v = (kv ? bv : bk)[hh * 64 + d]; }
    else v = bq[f - 1024];
    biasf[f] = v;
  }
}

// ---------------- LayerNorm fp32 -> bf16 ----------------
__global__ __launch_bounds__(256) void ln_kernel(const float* __restrict__ x,
                                                 const float* __restrict__ g,
                                                 const float* __restrict__ b,
                                                 unsigned short* __restrict__ h) {
  int wv = threadIdx.x >> 6, lane = threadIdx.x & 63;
  long row = (long)blockIdx.x * 4 + wv;
  const float* xr = x + row * DDIM + lane * 8;
  float4 v0 = *(const float4*)xr;
  float4 v1 = *(const float4*)(xr + 4);
  float s  = v0.x + v0.y + v0.z + v0.w + v1.x + v1.y + v1.z + v1.w;
  float s2 = v0.x*v0.x + v0.y*v0.y + v0.z*v0.z + v0.w*v0.w
           + v1.x*v1.x + v1.y*v1.y + v1.z*v1.z + v1.w*v1.w;
  #pragma unroll
  for (int o = 32; o; o >>= 1) { s += __shfl_xor(s, o); s2 += __shfl_xor(s2, o); }
  float mu = s * (1.0f / DDIM);
  float var = s2 * (1.0f / DDIM) - mu * mu;
  float rs = rsqrtf(var + 1e-5f);
  float4 g0 = *(const float4*)(g + lane * 8);
  float4 g1 = *(const float4*)(g + lane * 8 + 4);
  float4 b0 = *(const float4*)(b + lane * 8);
  float4 b1 = *(const float4*)(b + lane * 8 + 4);
  short8 o;
  o[0] = (short)f2bf((v0.x - mu) * rs * g0.x + b0.x);
  o[1] = (short)f2bf((v0.y - mu) * rs * g0.y + b0.y);
  o[2] = (short)f2bf((v0.z - mu) * rs * g0.z + b0.z);
  o[3] = (short)f2bf((v0.w - mu) * rs * g0.w + b0.w);
  o[4] = (short)f2bf((v1.x - mu) * rs * g1.x + b1.x);
  o[5] = (short)f2bf((v1.y - mu) * rs * g1.y + b1.y);
  o[6] = (short)f2bf((v1.z - mu) * rs * g1.z + b1.z);
  o[7] = (short)f2bf((v1.w - mu) * rs * g1.w + b1.w);
  *(short8*)(h + row * DDIM + lane * 8) = o;
}

// ---------------- fused QKV GEMM ----------------
// y<8: head-block -> partial kv (bf16 [64][64] + ksum row), nothing else to HBM.
// y>=8: q block -> elu+1, LDS-staged coalesced bf16 write.
__global__ __launch_bounds__(256) void qkv_gemm(const unsigned short* __restrict__ A,
                                                const unsigned short* __restrict__ wf,
                                                const float* __restrict__ biasf,
                                                unsigned short* __restrict__ qbuf,
                                                unsigned short* __restrict__ part) {
  __shared__ union {
    struct { unsigned short As[128 * 64]; unsigned short Bs[128 * 64]; } st;
    struct { unsigned short kT[64 * 136]; unsigned short vT[64 * 136]; } tr;
    unsigned short Cs[128 * 128];
  } sm;

  int t = threadIdx.x;
  int wv = t >> 6, lane = t & 63;
  int wm = wv >> 1, wn = wv & 1;
  int kg = lane >> 4, lr = lane & 15;

  // XCD swizzle: groups of 96 = 8 xcd-slots x 12 y-siblings (same A-panel -> same XCD L2)
  int lin = blockIdx.x;
  int g = lin / 96, r = lin % 96;
  int xb = g * 8 + (r & 7);
  int y  = r >> 3;                    // 0..11
  long mBase = (long)xb * 128;
  int nBase = y * 128;

  f32x4 acc[4][4];
  #pragma unroll
  for (int m = 0; m < 4; m++)
    #pragma unroll
    for (int n = 0; n < 4; n++) acc[m][n] = (f32x4){0.f, 0.f, 0.f, 0.f};

  const unsigned short* Ab = A + mBase * DDIM;
  const unsigned short* Wb = wf + (long)nBase * DDIM;

  for (int k0 = 0; k0 < DDIM; k0 += 64) {
    #pragma unroll
    for (int i = 0; i < 4; i++) {
      int c = i * 256 + t;
      int rr = c >> 3, cc = (c & 7) * 8;
      gload16(Ab + (long)rr * DDIM + k0 + cc, sm.st.As + c * 8);
      gload16(Wb + (long)rr * DDIM + k0 + cc, sm.st.Bs + c * 8);
    }
    __syncthreads();
    #pragma unroll
    for (int kk = 0; kk < 2; kk++) {
      int kl = kk * 32 + kg * 8;
      short8 a[4], b[4];
      #pragma unroll
      for (int m = 0; m < 4; m++)
        a[m] = *(const short8*)&sm.st.As[(wm * 64 + m * 16 + lr) * 64 + kl];
      #pragma unroll
      for (int n = 0; n < 4; n++)
        b[n] = *(const short8*)&sm.st.Bs[(wn * 64 + n * 16 + lr) * 64 + kl];
      #pragma unroll
      for (int m = 0; m < 4; m++)
        #pragma unroll
        for (int n = 0; n < 4; n++)
          acc[m][n] = __builtin_amdgcn_mfma_f32_16x16x32_bf16(a[m], b[n], acc[m][n], 0, 0, 0);
    }
    __syncthreads();
  }

  if (y < 8) {
    // ---- kv head block: write post-activation tiles transposed to LDS ----
    #pragma unroll
    for (int n = 0; n < 4; n++) {
      int col = wn * 64 + n * 16 + lr;          // 0..127: <64 -> k(d), >=64 -> v(e)
      float bv = biasf[nBase + col];
      #pragma unroll
      for (int m = 0; m < 4; m++)
        #pragma unroll
        for (int j = 0; j < 4; j++) {
          int row = wm * 64 + m * 16 + kg * 4 + j;  // token 0..127
          float v = acc[m][n][j] + bv;
          if (wn == 0) sm.tr.kT[col * 136 + row] = f2bf(elu1(v));
          else         sm.tr.vT[(col - 64) * 136 + row] = f2bf(v);
        }
    }
    __syncthreads();
    // ---- P = kT @ vT^T (64x64, K=128 tokens) via MFMA; wave wv owns d-rows wv*16.. ----
    f32x4 pacc[4];
    #pragma unroll
    for (int n = 0; n < 4; n++) pacc[n] = (f32x4){0.f, 0.f, 0.f, 0.f};
    short8 a[4];
    #pragma unroll
    for (int kk = 0; kk < 4; kk++)
      a[kk] = *(const short8*)&sm.tr.kT[(wv * 16 + lr) * 136 + kk * 32 + kg * 8];
    #pragma unroll
    for (int n = 0; n < 4; n++)
      #pragma unroll
      for (int kk = 0; kk < 4; kk++) {
        short8 b = *(const short8*)&sm.tr.vT[(n * 16 + lr) * 136 + kk * 32 + kg * 8];
        pacc[n] = __builtin_amdgcn_mfma_f32_16x16x32_bf16(a[kk], b, pacc[n], 0, 0, 0);
      }
    int batch = (int)(mBase / LTOK);
    int cIdx = xb % MBLK_B;
    long pbase = ((long)(batch * 8 + y) * MBLK_B + cIdx) * PTILE;
    #pragma unroll
    for (int n = 0; n < 4; n++)
      #pragma unroll
      for (int j = 0; j < 4; j++) {
        int d = wv * 16 + kg * 4 + j, e = n * 16 + lr;
        part[pbase + d * 64 + e] = f2bf(pacc[n][j]);
      }
    // ksum (post-elu k summed over 128 tokens)
    if (t < 64) {
      float s = 0.f;
      #pragma unroll
      for (int p = 0; p < 16; p++) {
        short8 kk8 = *(const short8*)&sm.tr.kT[t * 136 + p * 8];
        #pragma unroll
        for (int q = 0; q < 8; q++) s += bf2f((unsigned short)kk8[q]);
      }
      part[pbase + 4096 + t] = f2bf(s);
    }
  } else {
    // ---- q block: elu+1, LDS-stage, coalesced write ----
    #pragma unroll
    for (int n = 0; n < 4; n++) {
      int col = wn * 64 + n * 16 + lr;
      float bv = biasf[nBase + col];
      #pragma unroll
      for (int m = 0; m < 4; m++)
        #pragma unroll
        for (int j = 0; j < 4; j++) {
          int row = wm * 64 + m * 16 + kg * 4 + j;
          sm.Cs[row * 128 + col] = f2bf(elu1(acc[m][n][j] + bv));
        }
    }
    __syncthreads();
    int nq = y - 8;
    #pragma unroll
    for (int p = 0; p < 8; p++) {
      int idx = p * 256 + t;
      int row = idx >> 4, c8 = idx & 15;
      *(short8*)&qbuf[(mBase + row) * DDIM + nq * 128 + c8 * 8] =
          *(const short8*)&sm.Cs[row * 128 + c8 * 8];
    }
  }
}

// ---------------- reduce partials: kvT bf16 [bh][e*64+d], ksum fp32 ----------------
__global__ __launch_bounds__(256) void kv_final(const unsigned short* __restrict__ part,
                                                unsigned short* __restrict__ kvT,
                                                float* __restrict__ ksum) {
  int bh = blockIdx.x;
  int idx = blockIdx.y * 256 + threadIdx.x;
  if (idx >= PTILE) return;
  const unsigned short* base = part + (long)bh * MBLK_B * PTILE + idx;
  float s = 0.f;
  for (int c = 0; c < MBLK_B; c++) s += bf2f(base[(long)c * PTILE]);
  if (idx < 4096) {
    int d = idx >> 6, e = idx & 63;
    kvT[bh * 4096 + e * 64 + d] = f2bf(s);
  } else {
    ksum[bh * 64 + (idx - 4096)] = s;
  }
}

// ---------------- fused attention + output projection + residual ----------------
// per block: 128 rows x 256 out-cols; K-loop over 8 heads; A-tile = normalized attn built on the fly
__global__ __launch_bounds__(512) void attn_o(const unsigned short* __restrict__ qbuf,
                                              const unsigned short* __restrict__ kvT,
                                              const float* __restrict__ ksum,
                                              const unsigned short* __restrict__ wob,
                                              const float* __restrict__ bo,
                                              const float* __restrict__ xres,
                                              float* __restrict__ out) {
  __shared__ union {
    struct { unsigned short Qs[128 * 64]; unsigned short As[128 * 64]; unsigned short Bs[256 * 64]; } st;
    float Cs[128 * 128];
  } sm;

  int t = threadIdx.x;
  int wv = t >> 6, lane = t & 63;
  int kg = lane >> 4, lr = lane & 15;
  int wm = wv >> 2, wn = wv & 3;      // 2x4 wave grid: 64-row x 64-col tiles

  // XCD swizzle: groups of 16 = 8 xcd-slots x 2 y-siblings
  int lin = blockIdx.x;
  int g = lin >> 4, r = lin & 15;
  int xb = g * 8 + (r & 7);
  int y  = (r >> 3) & 1;
  long mBase = (long)xb * 128;
  int nBase = y * 256;
  int batch = (int)(mBase / LTOK);

  f32x4 acc[4][4];
  #pragma unroll
  for (int m = 0; m < 4; m++)
    #pragma unroll
    for (int n = 0; n < 4; n++) acc[m][n] = (f32x4){0.f, 0.f, 0.f, 0.f};

  for (int h = 0; h < NHEAD; h++) {
    int bh = batch * 8 + h;
    // stage q tile [128][64] and Wo slice [256][64]
    #pragma unroll
    for (int i = 0; i < 2; i++) {
      int c = i * 512 + t;
      int rr = c >> 3, cc = (c & 7) * 8;
      gload16(qbuf + (mBase + rr) * DDIM + h * 64 + cc, sm.st.Qs + c * 8);
    }
    #pragma unroll
    for (int i = 0; i < 4; i++) {
      int c = i * 512 + t;
      int rr = c >> 3, cc = (c & 7) * 8;
      gload16(wob + (long)(nBase + rr) * DDIM + h * 64 + cc, sm.st.Bs + c * 8);
    }
    __syncthreads();

    // ---- build normalized attn tile: wave wv owns rows wv*16..+15 ----
    short8 qa[2];
    #pragma unroll
    for (int kk = 0; kk < 2; kk++)
      qa[kk] = *(const short8*)&sm.st.Qs[(wv * 16 + lr) * 64 + kk * 32 + kg * 8];
    f32x4 pacc[4];
    #pragma unroll
    for (int n = 0; n < 4; n++) pacc[n] = (f32x4){0.f, 0.f, 0.f, 0.f};
    const unsigned short* kvb = kvT + bh * 4096;
    #pragma unroll
    for (int n = 0; n < 4; n++)
      #pragma unroll
      for (int kk = 0; kk < 2; kk++) {
        short8 b = *(const short8*)&kvb[(n * 16 + lr) * 64 + kk * 32 + kg * 8];
        pacc[n] = __builtin_amdgcn_mfma_f32_16x16x32_bf16(qa[kk], b, pacc[n], 0, 0, 0);
      }
    float na = 0.f;
    #pragma unroll
    for (int kk = 0; kk < 2; kk++)
      #pragma unroll
      for (int j = 0; j < 8; j++)
        na += bf2f((unsigned short)qa[kk][j]) * ksum[bh * 64 + kk * 32 + kg * 8 + j];
    na += __shfl_xor(na, 16);
    na += __shfl_xor(na, 32);    // every lane: norm for row (lane&15)
    #pragma unroll
    for (int n = 0; n < 4; n++)
      #pragma unroll
      for (int j = 0; j < 4; j++) {
        int rrow = kg * 4 + j;
        float norm = __shfl(na, rrow);
        float val = pacc[n][j] / (norm + 1e-6f);
        sm.st.As[(wv * 16 + rrow) * 64 + n * 16 + lr] = f2bf(val);
      }
    __syncthreads();

    // ---- O-GEMM step: acc += attn_tile @ Wo_slice^T ----
    #pragma unroll
    for (int kk = 0; kk < 2; kk++) {
      int kl = kk * 32 + kg * 8;
      short8 a[4], b[4];
      #pragma unroll
      for (int m = 0; m < 4; m++)
        a[m] = *(const short8*)&sm.st.As[(wm * 64 + m * 16 + lr) * 64 + kl];
      #pragma unroll
      for (int n = 0; n < 4; n++)
        b[n] = *(const short8*)&sm.st.Bs[(wn * 64 + n * 16 + lr) * 64 + kl];
      #pragma unroll
      for (int m = 0; m < 4; m++)
        #pragma unroll
        for (int n = 0; n < 4; n++)
          acc[m][n] = __builtin_amdgcn_mfma_f32_16x16x32_bf16(a[m], b[n], acc[m][n], 0, 0, 0);
    }
    __syncthreads();
  }

  // ---- epilogue: +bo, +residual, coalesced fp32 writes (two 128-col halves) ----
  for (int half = 0; half < 2; half++) {
    __syncthreads();
    if ((wn >> 1) == half) {
      #pragma unroll
      for (int n = 0; n < 4; n++) {
        int col = (wn & 1) * 64 + n * 16 + lr;
        float bv = bo[nBase + half * 128 + col];
        #pragma unroll
        for (int m = 0; m < 4; m++)
          #pragma unroll
          for (int j = 0; j < 4; j++) {
            int row = wm * 64 + m * 16 + kg * 4 + j;
            sm.Cs[row * 128 + col] = acc[m][n][j] + bv;
          }
      }
    }
    __syncthreads();
    #pragma unroll
    for (int p = 0; p < 8; p++) {
      int idx = p * 512 + t;
      int row = idx >> 5, c4 = idx & 31;
      long goff = (mBase + row) * DDIM + nBase + half * 128 + c4 * 4;
      float4 rv = *(const float4*)&xres[goff];
      float4 cv = *(const float4*)&sm.Cs[row * 128 + c4 * 4];
      float4 ov; ov.x = cv.x + rv.x; ov.y = cv.y + rv.y; ov.z = cv.z + rv.z; ov.w = cv.w + rv.w;
      *(float4*)&out[goff] = ov;
    }
  }
}

// ---------------- launcher ----------------
extern "C" void kernel_launch(void* const* d_in, const int* in_sizes, int n_in,
                              void* d_out, int out_size, void* d_ws, size_t ws_size,
                              hipStream_t stream) {
  const float* x    = (const float*)d_in[0];
  const float* Wq   = (const float*)d_in[1];
  const float* bq   = (const float*)d_in[2];
  const float* Wk   = (const float*)d_in[3];
  const float* bk   = (const float*)d_in[4];
  const float* Wv   = (const float*)d_in[5];
  const float* bv   = (const float*)d_in[6];
  const float* Wo   = (const float*)d_in[7];
  const float* bo   = (const float*)d_in[8];
  const float* ln_g = (const float*)d_in[9];
  const float* ln_b = (const float*)d_in[10];

  char* ws = (char*)d_ws;
  size_t SZ = (size_t)MROWS * DDIM * 2;                    // 100 MB bf16 buffer
  unsigned short* hbuf = (unsigned short*)ws;
  unsigned short* qbuf = (unsigned short*)(ws + SZ);
  char* p = ws + 2 * SZ;
  unsigned short* wf   = (unsigned short*)p;  p += (size_t)1536 * 512 * 2;
  unsigned short* wob  = (unsigned short*)p;  p += (size_t)512 * 512 * 2;
  float* biasf         = (float*)p;           p += 1536 * 4;
  p = (char*)(((uintptr_t)p + 255) & ~(uintptr_t)255);
  unsigned short* part = (unsigned short*)p;  p += (size_t)6144 * PTILE * 2;   // 51 MB
  unsigned short* kvT  = (unsigned short*)p;  p += (size_t)32 * 4096 * 2;
  float* ksum          = (float*)p;

  wprep<<<(786432 + 262144 + 1536 + 255) / 256, 256, 0, stream>>>(Wq, bq, Wk, bk, Wv, bv, Wo,
                                                                  wf, wob, biasf);
  ln_kernel<<<MROWS / 4, 256, 0, stream>>>(x, ln_g, ln_b, hbuf);
  qkv_gemm<<<MBLK * 12, 256, 0, stream>>>(hbuf, wf, biasf, qbuf, part);
  kv_final<<<dim3(32, (PTILE + 255) / 256), 256, 0, stream>>>(part, kvT, ksum);
  attn_o<<<MBLK * 2, 512, 0, stream>>>(qbuf, kvT, ksum, wob, bo, x, (float*)d_out);
}

// Round 3
// 652.355 us; speedup vs baseline: 1.4343x; 1.4343x over previous
//
#include <hip/hip_runtime.h>
#include <hip/hip_bf16.h>
#include <stdint.h>

#define DDIM 512
#define NHEAD 8
#define BATCH 4
#define LTOK 24576
#define MROWS 98304          // BATCH * LTOK
#define MBLK 768             // MROWS / 128
#define MBLK_B 192           // blocks per batch
#define PTILE 4160           // 64*64 kv + 64 ksum (bf16 elements)

typedef __attribute__((ext_vector_type(8))) short short8;
typedef __attribute__((ext_vector_type(4))) float f32x4;

__device__ __forceinline__ float bf2f(unsigned short u) {
  union { unsigned int i; float f; } c; c.i = ((unsigned int)u) << 16; return c.f;
}
__device__ __forceinline__ unsigned short f2bf(float f) {
  union { float f; unsigned int i; } c; c.f = f;
  unsigned int r = c.i + 0x7FFFu + ((c.i >> 16) & 1u);
  return (unsigned short)(r >> 16);
}
__device__ __forceinline__ void gload16(const void* g, void* l) {
  __builtin_amdgcn_global_load_lds((const __attribute__((address_space(1))) void*)g,
                                   (__attribute__((address_space(3))) void*)l, 16, 0, 0);
}
__device__ __forceinline__ float elu1(float v) { return (v > 0.f) ? (v + 1.f) : __expf(v); }

// ---------------- weight prep: fused QKV weights (head-interleaved) + Wo + fused bias ----------------
__global__ __launch_bounds__(256) void wprep(const float* __restrict__ Wq, const float* __restrict__ bq,
                                             const float* __restrict__ Wk, const float* __restrict__ bk,
                                             const float* __restrict__ Wv, const float* __restrict__ bv,
                                             const float* __restrict__ Wo,
                                             unsigned short* __restrict__ wf,
                                             unsigned short* __restrict__ wob,
                                             float* __restrict__ biasf) {
  long t = (long)blockIdx.x * 256 + threadIdx.x;
  if (t < 786432) {                       // 1536*512
    int f = (int)(t >> 9), c = (int)(t & 511);
    const float* src;
    if (f < 1024) { int hh = f >> 7, kv = (f >> 6) & 1, d = f & 63;
                    src = (kv ? Wv : Wk) + (long)(hh * 64 + d) * 512; }
    else          src = Wq + (long)(f - 1024) * 512;
    wf[t] = f2bf(src[c]);
  } else if (t < 786432 + 262144) {
    long i = t - 786432; wob[i] = f2bf(Wo[i]);
  } else if (t < 786432 + 262144 + 1536) {
    int f = (int)(t - (786432 + 262144));
    float v;
    if (f < 1024) { int hh = f >> 7, kv = (f >> 6) & 1, d = f & 63; v = (kv ? bv : bk)[hh * 64 + d]; }
    else v = bq[f - 1024];
    biasf[f] = v;
  }
}

// ---------------- LayerNorm fp32 -> bf16 ----------------
__global__ __launch_bounds__(256) void ln_kernel(const float* __restrict__ x,
                                                 const float* __restrict__ g,
                                                 const float* __restrict__ b,
                                                 unsigned short* __restrict__ h) {
  int wv = threadIdx.x >> 6, lane = threadIdx.x & 63;
  long row = (long)blockIdx.x * 4 + wv;
  const float* xr = x + row * DDIM + lane * 8;
  float4 v0 = *(const float4*)xr;
  float4 v1 = *(const float4*)(xr + 4);
  float s  = v0.x + v0.y + v0.z + v0.w + v1.x + v1.y + v1.z + v1.w;
  float s2 = v0.x*v0.x + v0.y*v0.y + v0.z*v0.z + v0.w*v0.w
           + v1.x*v1.x + v1.y*v1.y + v1.z*v1.z + v1.w*v1.w;
  #pragma unroll
  for (int o = 32; o; o >>= 1) { s += __shfl_xor(s, o); s2 += __shfl_xor(s2, o); }
  float mu = s * (1.0f / DDIM);
  float var = s2 * (1.0f / DDIM) - mu * mu;
  float rs = rsqrtf(var + 1e-5f);
  float4 g0 = *(const float4*)(g + lane * 8);
  float4 g1 = *(const float4*)(g + lane * 8 + 4);
  float4 b0 = *(const float4*)(b + lane * 8);
  float4 b1 = *(const float4*)(b + lane * 8 + 4);
  short8 o;
  o[0] = (short)f2bf((v0.x - mu) * rs * g0.x + b0.x);
  o[1] = (short)f2bf((v0.y - mu) * rs * g0.y + b0.y);
  o[2] = (short)f2bf((v0.z - mu) * rs * g0.z + b0.z);
  o[3] = (short)f2bf((v0.w - mu) * rs * g0.w + b0.w);
  o[4] = (short)f2bf((v1.x - mu) * rs * g1.x + b1.x);
  o[5] = (short)f2bf((v1.y - mu) * rs * g1.y + b1.y);
  o[6] = (short)f2bf((v1.z - mu) * rs * g1.z + b1.z);
  o[7] = (short)f2bf((v1.w - mu) * rs * g1.w + b1.w);
  *(short8*)(h + row * DDIM + lane * 8) = o;
}

// ---------------- fused QKV GEMM ----------------
// Tiles staged via global_load_lds with pre-swizzled source chunk (chunk ^= row&7);
// reads apply the same XOR -> 2-way max bank aliasing (free).
__global__ __launch_bounds__(256) void qkv_gemm(const unsigned short* __restrict__ A,
                                                const unsigned short* __restrict__ wf,
                                                const float* __restrict__ biasf,
                                                unsigned short* __restrict__ qbuf,
                                                unsigned short* __restrict__ part) {
  __shared__ union {
    struct { unsigned short As[128 * 64]; unsigned short Bs[128 * 64]; } st;
    struct { unsigned short kT[64 * 136]; unsigned short vT[64 * 136]; } tr;
    unsigned short Cs[128 * 136];     // padded q-staging tile
  } sm;

  int t = threadIdx.x;
  int wv = t >> 6, lane = t & 63;
  int wm = wv >> 1, wn = wv & 1;
  int kg = lane >> 4, lr = lane & 15;

  // XCD swizzle: groups of 96 = 8 xcd-slots x 12 y-siblings (same A-panel -> same XCD L2)
  int lin = blockIdx.x;
  int g = lin / 96, r = lin % 96;
  int xb = g * 8 + (r & 7);
  int y  = r >> 3;                    // 0..11
  long mBase = (long)xb * 128;
  int nBase = y * 128;

  f32x4 acc[4][4];
  #pragma unroll
  for (int m = 0; m < 4; m++)
    #pragma unroll
    for (int n = 0; n < 4; n++) acc[m][n] = (f32x4){0.f, 0.f, 0.f, 0.f};

  const unsigned short* Ab = A + mBase * DDIM;
  const unsigned short* Wb = wf + (long)nBase * DDIM;

  for (int k0 = 0; k0 < DDIM; k0 += 64) {
    #pragma unroll
    for (int i = 0; i < 4; i++) {
      int c = i * 256 + t;
      int rr = c >> 3, cc = c & 7;
      int sc = ((cc ^ (rr & 7)) << 3);          // pre-swizzled source chunk
      gload16(Ab + (long)rr * DDIM + k0 + sc, sm.st.As + c * 8);
      gload16(Wb + (long)rr * DDIM + k0 + sc, sm.st.Bs + c * 8);
    }
    __syncthreads();
    #pragma unroll
    for (int kk = 0; kk < 2; kk++) {
      short8 a[4], b[4];
      #pragma unroll
      for (int m = 0; m < 4; m++) {
        int row = wm * 64 + m * 16 + lr;
        a[m] = *(const short8*)&sm.st.As[row * 64 + (((kk * 4 + kg) ^ (row & 7)) << 3)];
      }
      #pragma unroll
      for (int n = 0; n < 4; n++) {
        int row = wn * 64 + n * 16 + lr;
        b[n] = *(const short8*)&sm.st.Bs[row * 64 + (((kk * 4 + kg) ^ (row & 7)) << 3)];
      }
      #pragma unroll
      for (int m = 0; m < 4; m++)
        #pragma unroll
        for (int n = 0; n < 4; n++)
          acc[m][n] = __builtin_amdgcn_mfma_f32_16x16x32_bf16(a[m], b[n], acc[m][n], 0, 0, 0);
    }
    __syncthreads();
  }

  if (y < 8) {
    // ---- kv head block: write post-activation tiles transposed to LDS (padded 136) ----
    #pragma unroll
    for (int n = 0; n < 4; n++) {
      int col = wn * 64 + n * 16 + lr;          // 0..127: <64 -> k(d), >=64 -> v(e)
      float bv = biasf[nBase + col];
      #pragma unroll
      for (int m = 0; m < 4; m++)
        #pragma unroll
        for (int j = 0; j < 4; j++) {
          int row = wm * 64 + m * 16 + kg * 4 + j;  // token 0..127
          float v = acc[m][n][j] + bv;
          if (wn == 0) sm.tr.kT[col * 136 + row] = f2bf(elu1(v));
          else         sm.tr.vT[(col - 64) * 136 + row] = f2bf(v);
        }
    }
    __syncthreads();
    // ---- P = kT @ vT^T (64x64, K=128 tokens) via MFMA ----
    f32x4 pacc[4];
    #pragma unroll
    for (int n = 0; n < 4; n++) pacc[n] = (f32x4){0.f, 0.f, 0.f, 0.f};
    short8 a[4];
    #pragma unroll
    for (int kk = 0; kk < 4; kk++)
      a[kk] = *(const short8*)&sm.tr.kT[(wv * 16 + lr) * 136 + kk * 32 + kg * 8];
    #pragma unroll
    for (int n = 0; n < 4; n++)
      #pragma unroll
      for (int kk = 0; kk < 4; kk++) {
        short8 b = *(const short8*)&sm.tr.vT[(n * 16 + lr) * 136 + kk * 32 + kg * 8];
        pacc[n] = __builtin_amdgcn_mfma_f32_16x16x32_bf16(a[kk], b, pacc[n], 0, 0, 0);
      }
    int batch = (int)(mBase / LTOK);
    int cIdx = xb % MBLK_B;
    long pbase = ((long)(batch * 8 + y) * MBLK_B + cIdx) * PTILE;
    #pragma unroll
    for (int n = 0; n < 4; n++)
      #pragma unroll
      for (int j = 0; j < 4; j++) {
        int d = wv * 16 + kg * 4 + j, e = n * 16 + lr;
        part[pbase + d * 64 + e] = f2bf(pacc[n][j]);
      }
    if (t < 64) {
      float s = 0.f;
      #pragma unroll
      for (int p = 0; p < 16; p++) {
        short8 kk8 = *(const short8*)&sm.tr.kT[t * 136 + p * 8];
        #pragma unroll
        for (int q = 0; q < 8; q++) s += bf2f((unsigned short)kk8[q]);
      }
      part[pbase + 4096 + t] = f2bf(s);
    }
  } else {
    // ---- q block: elu+1, padded-LDS stage, coalesced write ----
    #pragma unroll
    for (int n = 0; n < 4; n++) {
      int col = wn * 64 + n * 16 + lr;
      float bv = biasf[nBase + col];
      #pragma unroll
      for (int m = 0; m < 4; m++)
        #pragma unroll
        for (int j = 0; j < 4; j++) {
          int row = wm * 64 + m * 16 + kg * 4 + j;
          sm.Cs[row * 136 + col] = f2bf(elu1(acc[m][n][j] + bv));
        }
    }
    __syncthreads();
    int nq = y - 8;
    #pragma unroll
    for (int p = 0; p < 8; p++) {
      int idx = p * 256 + t;
      int row = idx >> 4, c8 = idx & 15;
      *(short8*)&qbuf[(mBase + row) * DDIM + nq * 128 + c8 * 8] =
          *(const short8*)&sm.Cs[row * 136 + c8 * 8];
    }
  }
}

// ---------------- reduce partials: kvT bf16 [bh][e*64+d], ksum fp32 ----------------
__global__ __launch_bounds__(256) void kv_final(const unsigned short* __restrict__ part,
                                                unsigned short* __restrict__ kvT,
                                                float* __restrict__ ksum) {
  int bh = blockIdx.x;
  int idx = blockIdx.y * 256 + threadIdx.x;
  if (idx >= PTILE) return;
  const unsigned short* base = part + (long)bh * MBLK_B * PTILE + idx;
  float s = 0.f;
  for (int c = 0; c < MBLK_B; c++) s += bf2f(base[(long)c * PTILE]);
  if (idx < 4096) {
    int d = idx >> 6, e = idx & 63;
    kvT[bh * 4096 + e * 64 + d] = f2bf(s);
  } else {
    ksum[bh * 64 + (idx - 4096)] = s;
  }
}

// ---------------- fused attention + output projection + residual ----------------
__global__ __launch_bounds__(512) void attn_o(const unsigned short* __restrict__ qbuf,
                                              const unsigned short* __restrict__ kvT,
                                              const float* __restrict__ ksum,
                                              const unsigned short* __restrict__ wob,
                                              const float* __restrict__ bo,
                                              const float* __restrict__ xres,
                                              float* __restrict__ out) {
  __shared__ union {
    struct { unsigned short Qs[128 * 64]; unsigned short As[128 * 72]; unsigned short Bs[256 * 64]; } st;
    float Cs[128 * 128];
  } sm;

  int t = threadIdx.x;
  int wv = t >> 6, lane = t & 63;
  int kg = lane >> 4, lr = lane & 15;
  int wm = wv >> 2, wn = wv & 3;      // 2x4 wave grid: 64-row x 64-col tiles

  // XCD swizzle: groups of 16 = 8 xcd-slots x 2 y-siblings
  int lin = blockIdx.x;
  int g = lin >> 4, r = lin & 15;
  int xb = g * 8 + (r & 7);
  int y  = (r >> 3) & 1;
  long mBase = (long)xb * 128;
  int nBase = y * 256;
  int batch = (int)(mBase / LTOK);

  f32x4 acc[4][4];
  #pragma unroll
  for (int m = 0; m < 4; m++)
    #pragma unroll
    for (int n = 0; n < 4; n++) acc[m][n] = (f32x4){0.f, 0.f, 0.f, 0.f};

  for (int h = 0; h < NHEAD; h++) {
    int bh = batch * 8 + h;
    // stage q tile [128][64] and Wo slice [256][64] with pre-swizzled source chunk
    #pragma unroll
    for (int i = 0; i < 2; i++) {
      int c = i * 512 + t;
      int rr = c >> 3, cc = c & 7;
      int sc = ((cc ^ (rr & 7)) << 3);
      gload16(qbuf + (mBase + rr) * DDIM + h * 64 + sc, sm.st.Qs + c * 8);
    }
    #pragma unroll
    for (int i = 0; i < 4; i++) {
      int c = i * 512 + t;
      int rr = c >> 3, cc = c & 7;
      int sc = ((cc ^ (rr & 7)) << 3);
      gload16(wob + (long)(nBase + rr) * DDIM + h * 64 + sc, sm.st.Bs + c * 8);
    }
    __syncthreads();

    // ---- build normalized attn tile: wave wv owns rows wv*16..+15 ----
    int qrow = wv * 16 + lr;
    short8 qa[2];
    #pragma unroll
    for (int kk = 0; kk < 2; kk++)
      qa[kk] = *(const short8*)&sm.st.Qs[qrow * 64 + (((kk * 4 + kg) ^ (qrow & 7)) << 3)];
    f32x4 pacc[4];
    #pragma unroll
    for (int n = 0; n < 4; n++) pacc[n] = (f32x4){0.f, 0.f, 0.f, 0.f};
    const unsigned short* kvb = kvT + bh * 4096;
    #pragma unroll
    for (int n = 0; n < 4; n++)
      #pragma unroll
      for (int kk = 0; kk < 2; kk++) {
        short8 b = *(const short8*)&kvb[(n * 16 + lr) * 64 + kk * 32 + kg * 8];
        pacc[n] = __builtin_amdgcn_mfma_f32_16x16x32_bf16(qa[kk], b, pacc[n], 0, 0, 0);
      }
    float na = 0.f;
    #pragma unroll
    for (int kk = 0; kk < 2; kk++)
      #pragma unroll
      for (int j = 0; j < 8; j++)
        na += bf2f((unsigned short)qa[kk][j]) * ksum[bh * 64 + kk * 32 + kg * 8 + j];
    na += __shfl_xor(na, 16);
    na += __shfl_xor(na, 32);    // every lane: norm for row (lane&15)
    #pragma unroll
    for (int n = 0; n < 4; n++)
      #pragma unroll
      for (int j = 0; j < 4; j++) {
        int rrow = kg * 4 + j;
        float norm = __shfl(na, rrow);
        float val = pacc[n][j] / (norm + 1e-6f);
        sm.st.As[(wv * 16 + rrow) * 72 + n * 16 + lr] = f2bf(val);
      }
    __syncthreads();

    // ---- O-GEMM step: acc += attn_tile @ Wo_slice^T ----
    #pragma unroll
    for (int kk = 0; kk < 2; kk++) {
      int kl = kk * 32 + kg * 8;
      short8 a[4], b[4];
      #pragma unroll
      for (int m = 0; m < 4; m++)
        a[m] = *(const short8*)&sm.st.As[(wm * 64 + m * 16 + lr) * 72 + kl];
      #pragma unroll
      for (int n = 0; n < 4; n++) {
        int row = wn * 64 + n * 16 + lr;
        b[n] = *(const short8*)&sm.st.Bs[row * 64 + (((kk * 4 + kg) ^ (row & 7)) << 3)];
      }
      #pragma unroll
      for (int m = 0; m < 4; m++)
        #pragma unroll
        for (int n = 0; n < 4; n++)
          acc[m][n] = __builtin_amdgcn_mfma_f32_16x16x32_bf16(a[m], b[n], acc[m][n], 0, 0, 0);
    }
    __syncthreads();
  }

  // ---- epilogue: +bo, +residual, coalesced fp32 writes (two 128-col halves) ----
  for (int half = 0; half < 2; half++) {
    __syncthreads();
    if ((wn >> 1) == half) {
      #pragma unroll
      for (int n = 0; n < 4; n++) {
        int col = (wn & 1) * 64 + n * 16 + lr;
        float bv = bo[nBase + half * 128 + col];
        #pragma unroll
        for (int m = 0; m < 4; m++)
          #pragma unroll
          for (int j = 0; j < 4; j++) {
            int row = wm * 64 + m * 16 + kg * 4 + j;
            sm.Cs[row * 128 + col] = acc[m][n][j] + bv;
          }
      }
    }
    __syncthreads();
    #pragma unroll
    for (int p = 0; p < 8; p++) {
      int idx = p * 512 + t;
      int row = idx >> 5, c4 = idx & 31;
      long goff = (mBase + row) * DDIM + nBase + half * 128 + c4 * 4;
      float4 rv = *(const float4*)&xres[goff];
      float4 cv = *(const float4*)&sm.Cs[row * 128 + c4 * 4];
      float4 ov; ov.x = cv.x + rv.x; ov.y = cv.y + rv.y; ov.z = cv.z + rv.z; ov.w = cv.w + rv.w;
      *(float4*)&out[goff] = ov;
    }
  }
}

// ---------------- launcher ----------------
extern "C" void kernel_launch(void* const* d_in, const int* in_sizes, int n_in,
                              void* d_out, int out_size, void* d_ws, size_t ws_size,
                              hipStream_t stream) {
  const float* x    = (const float*)d_in[0];
  const float* Wq   = (const float*)d_in[1];
  const float* bq   = (const float*)d_in[2];
  const float* Wk   = (const float*)d_in[3];
  const float* bk   = (const float*)d_in[4];
  const float* Wv   = (const float*)d_in[5];
  const float* bv   = (const float*)d_in[6];
  const float* Wo   = (const float*)d_in[7];
  const float* bo   = (const float*)d_in[8];
  const float* ln_g = (const float*)d_in[9];
  const float* ln_b = (const float*)d_in[10];

  char* ws = (char*)d_ws;
  size_t SZ = (size_t)MROWS * DDIM * 2;                    // 100 MB bf16 buffer
  unsigned short* hbuf = (unsigned short*)ws;
  unsigned short* qbuf = (unsigned short*)(ws + SZ);
  char* p = ws + 2 * SZ;
  unsigned short* wf   = (unsigned short*)p;  p += (size_t)1536 * 512 * 2;
  unsigned short* wob  = (unsigned short*)p;  p += (size_t)512 * 512 * 2;
  float* biasf         = (float*)p;           p += 1536 * 4;
  p = (char*)(((uintptr_t)p + 255) & ~(uintptr_t)255);
  unsigned short* part = (unsigned short*)p;  p += (size_t)6144 * PTILE * 2;   // 51 MB
  unsigned short* kvT  = (unsigned short*)p;  p += (size_t)32 * 4096 * 2;
  float* ksum          = (float*)p;

  wprep<<<(786432 + 262144 + 1536 + 255) / 256, 256, 0, stream>>>(Wq, bq, Wk, bk, Wv, bv, Wo,
                                                                  wf, wob, biasf);
  ln_kernel<<<MROWS / 4, 256, 0, stream>>>(x, ln_g, ln_b, hbuf);
  qkv_gemm<<<MBLK * 12, 256, 0, stream>>>(hbuf, wf, biasf, qbuf, part);
  kv_final<<<dim3(32, (PTILE + 255) / 256), 256, 0, stream>>>(part, kvT, ksum);
  attn_o<<<MBLK * 2, 512, 0, stream>>>(qbuf, kvT, ksum, wob, bo, x, (float*)d_out);
}

// Round 4
// 511.428 us; speedup vs baseline: 1.8295x; 1.2756x over previous
//
#include <hip/hip_runtime.h>
#include <hip/hip_bf16.h>
#include <stdint.h>

#define DDIM 512
#define NHEAD 8
#define BATCH 4
#define LTOK 24576
#define MROWS 98304          // BATCH * LTOK
#define MBLK 768             // MROWS / 128
#define MBLK_B 192           // blocks per batch
#define PTILE 4160           // 64*64 kv + 64 ksum (bf16 elements)

typedef __attribute__((ext_vector_type(8))) short short8;
typedef __attribute__((ext_vector_type(4))) float f32x4;

__device__ __forceinline__ float bf2f(unsigned short u) {
  union { unsigned int i; float f; } c; c.i = ((unsigned int)u) << 16; return c.f;
}
__device__ __forceinline__ unsigned short f2bf(float f) {
  union { float f; unsigned int i; } c; c.f = f;
  unsigned int r = c.i + 0x7FFFu + ((c.i >> 16) & 1u);
  return (unsigned short)(r >> 16);
}
__device__ __forceinline__ void gload16(const void* g, void* l) {
  __builtin_amdgcn_global_load_lds((const __attribute__((address_space(1))) void*)g,
                                   (__attribute__((address_space(3))) void*)l, 16, 0, 0);
}
__device__ __forceinline__ float elu1(float v) { return (v > 0.f) ? (v + 1.f) : __expf(v); }

// ---------------- weight prep: fused QKV weights (head-interleaved) + Wo + fused bias ----------------
__global__ __launch_bounds__(256) void wprep(const float* __restrict__ Wq, const float* __restrict__ bq,
                                             const float* __restrict__ Wk, const float* __restrict__ bk,
                                             const float* __restrict__ Wv, const float* __restrict__ bv,
                                             const float* __restrict__ Wo,
                                             unsigned short* __restrict__ wf,
                                             unsigned short* __restrict__ wob,
                                             float* __restrict__ biasf) {
  long t = (long)blockIdx.x * 256 + threadIdx.x;
  if (t < 786432) {                       // 1536*512
    int f = (int)(t >> 9), c = (int)(t & 511);
    const float* src;
    if (f < 1024) { int hh = f >> 7, kv = (f >> 6) & 1, d = f & 63;
                    src = (kv ? Wv : Wk) + (long)(hh * 64 + d) * 512; }
    else          src = Wq + (long)(f - 1024) * 512;
    wf[t] = f2bf(src[c]);
  } else if (t < 786432 + 262144) {
    long i = t - 786432; wob[i] = f2bf(Wo[i]);
  } else if (t < 786432 + 262144 + 1536) {
    int f = (int)(t - (786432 + 262144));
    float v;
    if (f < 1024) { int hh = f >> 7, kv = (f >> 6) & 1, d = f & 63; v = (kv ? bv : bk)[hh * 64 + d]; }
    else v = bq[f - 1024];
    biasf[f] = v;
  }
}

// ---------------- LayerNorm fp32 -> bf16 ----------------
__global__ __launch_bounds__(256) void ln_kernel(const float* __restrict__ x,
                                                 const float* __restrict__ g,
                                                 const float* __restrict__ b,
                                                 unsigned short* __restrict__ h) {
  int wv = threadIdx.x >> 6, lane = threadIdx.x & 63;
  long row = (long)blockIdx.x * 4 + wv;
  const float* xr = x + row * DDIM + lane * 8;
  float4 v0 = *(const float4*)xr;
  float4 v1 = *(const float4*)(xr + 4);
  float s  = v0.x + v0.y + v0.z + v0.w + v1.x + v1.y + v1.z + v1.w;
  float s2 = v0.x*v0.x + v0.y*v0.y + v0.z*v0.z + v0.w*v0.w
           + v1.x*v1.x + v1.y*v1.y + v1.z*v1.z + v1.w*v1.w;
  #pragma unroll
  for (int o = 32; o; o >>= 1) { s += __shfl_xor(s, o); s2 += __shfl_xor(s2, o); }
  float mu = s * (1.0f / DDIM);
  float var = s2 * (1.0f / DDIM) - mu * mu;
  float rs = rsqrtf(var + 1e-5f);
  float4 g0 = *(const float4*)(g + lane * 8);
  float4 g1 = *(const float4*)(g + lane * 8 + 4);
  float4 b0 = *(const float4*)(b + lane * 8);
  float4 b1 = *(const float4*)(b + lane * 8 + 4);
  short8 o;
  o[0] = (short)f2bf((v0.x - mu) * rs * g0.x + b0.x);
  o[1] = (short)f2bf((v0.y - mu) * rs * g0.y + b0.y);
  o[2] = (short)f2bf((v0.z - mu) * rs * g0.z + b0.z);
  o[3] = (short)f2bf((v0.w - mu) * rs * g0.w + b0.w);
  o[4] = (short)f2bf((v1.x - mu) * rs * g1.x + b1.x);
  o[5] = (short)f2bf((v1.y - mu) * rs * g1.y + b1.y);
  o[6] = (short)f2bf((v1.z - mu) * rs * g1.z + b1.z);
  o[7] = (short)f2bf((v1.w - mu) * rs * g1.w + b1.w);
  *(short8*)(h + row * DDIM + lane * 8) = o;
}

// ---------------- fused QKV GEMM ----------------
// y<8: head-block -> partial kv + ksum; y>=8: q block -> elu+1, coalesced bf16 write.
__global__ __launch_bounds__(256) void qkv_gemm(const unsigned short* __restrict__ A,
                                                const unsigned short* __restrict__ wf,
                                                const float* __restrict__ biasf,
                                                unsigned short* __restrict__ qbuf,
                                                unsigned short* __restrict__ part) {
  __shared__ union {
    struct { unsigned short As[128 * 64]; unsigned short Bs[128 * 64]; } st;
    struct { unsigned short kT[64 * 136]; unsigned short vT[64 * 136]; } tr;
    unsigned short Cs[128 * 136];     // padded q-staging tile
  } sm;

  int t = threadIdx.x;
  int wv = t >> 6, lane = t & 63;
  int wm = wv >> 1, wn = wv & 1;
  int kg = lane >> 4, lr = lane & 15;

  // XCD swizzle: groups of 96 = 8 xcd-slots x 12 y-siblings
  int lin = blockIdx.x;
  int g = lin / 96, r = lin % 96;
  int xb = g * 8 + (r & 7);
  int y  = r >> 3;                    // 0..11
  long mBase = (long)xb * 128;
  int nBase = y * 128;

  f32x4 acc[4][4];
  #pragma unroll
  for (int m = 0; m < 4; m++)
    #pragma unroll
    for (int n = 0; n < 4; n++) acc[m][n] = (f32x4){0.f, 0.f, 0.f, 0.f};

  const unsigned short* Ab = A + mBase * DDIM;
  const unsigned short* Wb = wf + (long)nBase * DDIM;

  for (int k0 = 0; k0 < DDIM; k0 += 64) {
    #pragma unroll
    for (int i = 0; i < 4; i++) {
      int c = i * 256 + t;
      int rr = c >> 3, cc = c & 7;
      int sc = ((cc ^ (rr & 7)) << 3);          // pre-swizzled source chunk
      gload16(Ab + (long)rr * DDIM + k0 + sc, sm.st.As + c * 8);
      gload16(Wb + (long)rr * DDIM + k0 + sc, sm.st.Bs + c * 8);
    }
    __syncthreads();
    #pragma unroll
    for (int kk = 0; kk < 2; kk++) {
      short8 a[4], b[4];
      #pragma unroll
      for (int m = 0; m < 4; m++) {
        int row = wm * 64 + m * 16 + lr;
        a[m] = *(const short8*)&sm.st.As[row * 64 + (((kk * 4 + kg) ^ (row & 7)) << 3)];
      }
      #pragma unroll
      for (int n = 0; n < 4; n++) {
        int row = wn * 64 + n * 16 + lr;
        b[n] = *(const short8*)&sm.st.Bs[row * 64 + (((kk * 4 + kg) ^ (row & 7)) << 3)];
      }
      #pragma unroll
      for (int m = 0; m < 4; m++)
        #pragma unroll
        for (int n = 0; n < 4; n++)
          acc[m][n] = __builtin_amdgcn_mfma_f32_16x16x32_bf16(a[m], b[n], acc[m][n], 0, 0, 0);
    }
    __syncthreads();
  }

  if (y < 8) {
    // ---- kv head block: write post-activation tiles transposed to LDS (padded 136) ----
    #pragma unroll
    for (int n = 0; n < 4; n++) {
      int col = wn * 64 + n * 16 + lr;          // 0..127: <64 -> k(d), >=64 -> v(e)
      float bv = biasf[nBase + col];
      #pragma unroll
      for (int m = 0; m < 4; m++)
        #pragma unroll
        for (int j = 0; j < 4; j++) {
          int row = wm * 64 + m * 16 + kg * 4 + j;  // token 0..127
          float v = acc[m][n][j] + bv;
          if (wn == 0) sm.tr.kT[col * 136 + row] = f2bf(elu1(v));
          else         sm.tr.vT[(col - 64) * 136 + row] = f2bf(v);
        }
    }
    __syncthreads();
    // ---- P = kT @ vT^T (64x64, K=128 tokens) via MFMA ----
    f32x4 pacc[4];
    #pragma unroll
    for (int n = 0; n < 4; n++) pacc[n] = (f32x4){0.f, 0.f, 0.f, 0.f};
    short8 a[4];
    #pragma unroll
    for (int kk = 0; kk < 4; kk++)
      a[kk] = *(const short8*)&sm.tr.kT[(wv * 16 + lr) * 136 + kk * 32 + kg * 8];
    #pragma unroll
    for (int n = 0; n < 4; n++)
      #pragma unroll
      for (int kk = 0; kk < 4; kk++) {
        short8 b = *(const short8*)&sm.tr.vT[(n * 16 + lr) * 136 + kk * 32 + kg * 8];
        pacc[n] = __builtin_amdgcn_mfma_f32_16x16x32_bf16(a[kk], b, pacc[n], 0, 0, 0);
      }
    int batch = (int)(mBase / LTOK);
    int cIdx = xb % MBLK_B;
    long pbase = ((long)(batch * 8 + y) * MBLK_B + cIdx) * PTILE;
    #pragma unroll
    for (int n = 0; n < 4; n++)
      #pragma unroll
      for (int j = 0; j < 4; j++) {
        int d = wv * 16 + kg * 4 + j, e = n * 16 + lr;
        part[pbase + d * 64 + e] = f2bf(pacc[n][j]);
      }
    if (t < 64) {
      float s = 0.f;
      #pragma unroll
      for (int p = 0; p < 16; p++) {
        short8 kk8 = *(const short8*)&sm.tr.kT[t * 136 + p * 8];
        #pragma unroll
        for (int q = 0; q < 8; q++) s += bf2f((unsigned short)kk8[q]);
      }
      part[pbase + 4096 + t] = f2bf(s);
    }
  } else {
    // ---- q block: elu+1, padded-LDS stage, coalesced write ----
    #pragma unroll
    for (int n = 0; n < 4; n++) {
      int col = wn * 64 + n * 16 + lr;
      float bv = biasf[nBase + col];
      #pragma unroll
      for (int m = 0; m < 4; m++)
        #pragma unroll
        for (int j = 0; j < 4; j++) {
          int row = wm * 64 + m * 16 + kg * 4 + j;
          sm.Cs[row * 136 + col] = f2bf(elu1(acc[m][n][j] + bv));
        }
    }
    __syncthreads();
    int nq = y - 8;
    #pragma unroll
    for (int p = 0; p < 8; p++) {
      int idx = p * 256 + t;
      int row = idx >> 4, c8 = idx & 15;
      *(short8*)&qbuf[(mBase + row) * DDIM + nq * 128 + c8 * 8] =
          *(const short8*)&sm.Cs[row * 136 + c8 * 8];
    }
  }
}

// ---------------- reduce partials: kvD bf16 [bh][d*64+e], ksum fp32 ----------------
__global__ __launch_bounds__(256) void kv_final(const unsigned short* __restrict__ part,
                                                unsigned short* __restrict__ kvD,
                                                float* __restrict__ ksum) {
  int bh = blockIdx.x;
  int idx = blockIdx.y * 256 + threadIdx.x;
  if (idx >= PTILE) return;
  const unsigned short* base = part + (long)bh * MBLK_B * PTILE + idx;
  float s = 0.f;
  for (int c = 0; c < MBLK_B; c++) s += bf2f(base[(long)c * PTILE]);
  if (idx < 4096) kvD[bh * 4096 + idx] = f2bf(s);   // layout [d][e]
  else            ksum[bh * 64 + (idx - 4096)] = s;
}

// ---------------- W2[b,h] = kv_h @ Wo_h^T, written as Bmat[b][c][h*64+d] ----------------
__global__ __launch_bounds__(512) void w2_gemm(const unsigned short* __restrict__ kvD,
                                               const unsigned short* __restrict__ wob,
                                               unsigned short* __restrict__ Bmat) {
  __shared__ unsigned short W2s[512 * 72];
  int t = threadIdx.x, wv = t >> 6, lane = t & 63;
  int kg = lane >> 4, lr = lane & 15;
  int bh = blockIdx.x, b = bh >> 3, h = bh & 7;
  const unsigned short* kva = kvD + bh * 4096;

  short8 a[4][2];
  #pragma unroll
  for (int m = 0; m < 4; m++)
    #pragma unroll
    for (int kk = 0; kk < 2; kk++)
      a[m][kk] = *(const short8*)&kva[(m * 16 + lr) * 64 + kk * 32 + kg * 8];

  f32x4 acc[4][4];
  #pragma unroll
  for (int m = 0; m < 4; m++)
    #pragma unroll
    for (int n = 0; n < 4; n++) acc[m][n] = (f32x4){0.f, 0.f, 0.f, 0.f};

  #pragma unroll
  for (int n = 0; n < 4; n++) {
    int c = wv * 64 + n * 16 + lr;
    #pragma unroll
    for (int kk = 0; kk < 2; kk++) {
      short8 bfr = *(const short8*)&wob[(long)c * 512 + h * 64 + kk * 32 + kg * 8];
      #pragma unroll
      for (int m = 0; m < 4; m++)
        acc[m][n] = __builtin_amdgcn_mfma_f32_16x16x32_bf16(a[m][kk], bfr, acc[m][n], 0, 0, 0);
    }
  }
  // transpose through LDS: W2s[c][d]
  #pragma unroll
  for (int m = 0; m < 4; m++)
    #pragma unroll
    for (int n = 0; n < 4; n++)
      #pragma unroll
      for (int j = 0; j < 4; j++)
        W2s[(wv * 64 + n * 16 + lr) * 72 + m * 16 + kg * 4 + j] = f2bf(acc[m][n][j]);
  __syncthreads();
  #pragma unroll
  for (int pp = 0; pp < 8; pp++) {
    int idx = pp * 512 + t;
    int c = idx >> 3, ch = (idx & 7) * 8;
    *(short8*)&Bmat[(long)b * 262144 + (long)c * 512 + h * 64 + ch] =
        *(const short8*)&W2s[c * 72 + ch];
  }
}

// ---------------- scale q rows in place: qs = q / (q . ksum_h + eps) ----------------
__global__ __launch_bounds__(256) void qscale(unsigned short* __restrict__ q,
                                              const float* __restrict__ ksum) {
  int wv = threadIdx.x >> 6, lane = threadIdx.x & 63;
  long row = (long)blockIdx.x * 4 + wv;
  int batch = (int)(row / LTOK);
  int bh = batch * 8 + (lane >> 3);
  unsigned short* qr = q + row * DDIM + lane * 8;
  short8 qv = *(const short8*)qr;
  const float* ks = ksum + bh * 64 + (lane & 7) * 8;
  float4 k0 = *(const float4*)ks;
  float4 k1 = *(const float4*)(ks + 4);
  float qf[8];
  #pragma unroll
  for (int j = 0; j < 8; j++) qf[j] = bf2f((unsigned short)qv[j]);
  float n = qf[0]*k0.x + qf[1]*k0.y + qf[2]*k0.z + qf[3]*k0.w
          + qf[4]*k1.x + qf[5]*k1.y + qf[6]*k1.z + qf[7]*k1.w;
  n += __shfl_xor(n, 1);
  n += __shfl_xor(n, 2);
  n += __shfl_xor(n, 4);
  float s = 1.0f / (n + 1e-6f);
  short8 o;
  #pragma unroll
  for (int j = 0; j < 8; j++) o[j] = (short)f2bf(qf[j] * s);
  *(short8*)qr = o;
}

// ---------------- final GEMM: out = qs @ Bmat[b]^T + bo + x ----------------
__global__ __launch_bounds__(256) void ogemm(const unsigned short* __restrict__ A,
                                             const unsigned short* __restrict__ Bm,
                                             const float* __restrict__ bo,
                                             const float* __restrict__ xres,
                                             float* __restrict__ out) {
  __shared__ union {
    struct { unsigned short As[128 * 64]; unsigned short Bs[128 * 64]; } st;
    float Cs[64 * 132];
  } sm;

  int t = threadIdx.x;
  int wv = t >> 6, lane = t & 63;
  int wm = wv >> 1, wn = wv & 1;
  int kg = lane >> 4, lr = lane & 15;

  // XCD swizzle: groups of 32 = 8 xcd-slots x 4 y-siblings
  int lin = blockIdx.x;
  int g = lin >> 5, r = lin & 31;
  int xb = g * 8 + (r & 7);
  int y  = r >> 3;                    // 0..3
  long mBase = (long)xb * 128;
  int nBase = y * 128;
  int batch = xb / MBLK_B;

  f32x4 acc[4][4];
  #pragma unroll
  for (int m = 0; m < 4; m++)
    #pragma unroll
    for (int n = 0; n < 4; n++) acc[m][n] = (f32x4){0.f, 0.f, 0.f, 0.f};

  const unsigned short* Ab = A + mBase * DDIM;
  const unsigned short* Bb = Bm + (long)batch * 262144 + (long)nBase * DDIM;

  for (int k0 = 0; k0 < DDIM; k0 += 64) {
    #pragma unroll
    for (int i = 0; i < 4; i++) {
      int c = i * 256 + t;
      int rr = c >> 3, cc = c & 7;
      int sc = ((cc ^ (rr & 7)) << 3);
      gload16(Ab + (long)rr * DDIM + k0 + sc, sm.st.As + c * 8);
      gload16(Bb + (long)rr * DDIM + k0 + sc, sm.st.Bs + c * 8);
    }
    __syncthreads();
    #pragma unroll
    for (int kk = 0; kk < 2; kk++) {
      short8 a[4], b[4];
      #pragma unroll
      for (int m = 0; m < 4; m++) {
        int row = wm * 64 + m * 16 + lr;
        a[m] = *(const short8*)&sm.st.As[row * 64 + (((kk * 4 + kg) ^ (row & 7)) << 3)];
      }
      #pragma unroll
      for (int n = 0; n < 4; n++) {
        int row = wn * 64 + n * 16 + lr;
        b[n] = *(const short8*)&sm.st.Bs[row * 64 + (((kk * 4 + kg) ^ (row & 7)) << 3)];
      }
      #pragma unroll
      for (int m = 0; m < 4; m++)
        #pragma unroll
        for (int n = 0; n < 4; n++)
          acc[m][n] = __builtin_amdgcn_mfma_f32_16x16x32_bf16(a[m], b[n], acc[m][n], 0, 0, 0);
    }
    __syncthreads();
  }

  // epilogue: +bo, +residual via LDS (two 64-row passes), coalesced fp32 writes
  for (int p = 0; p < 2; p++) {
    __syncthreads();
    if (wm == p) {
      #pragma unroll
      for (int n = 0; n < 4; n++) {
        int col = wn * 64 + n * 16 + lr;
        float bv = bo[nBase + col];
        #pragma unroll
        for (int m = 0; m < 4; m++)
          #pragma unroll
          for (int j = 0; j < 4; j++) {
            int lrow = m * 16 + kg * 4 + j;
            sm.Cs[lrow * 132 + col] = acc[m][n][j] + bv;
          }
      }
    }
    __syncthreads();
    #pragma unroll
    for (int pp = 0; pp < 8; pp++) {
      int idx = pp * 256 + t;
      int row = idx >> 5, c4 = idx & 31;
      long goff = (mBase + p * 64 + row) * DDIM + nBase + c4 * 4;
      float4 rv = *(const float4*)&xres[goff];
      float4 cv = *(const float4*)&sm.Cs[row * 132 + c4 * 4];
      float4 ov; ov.x = cv.x + rv.x; ov.y = cv.y + rv.y; ov.z = cv.z + rv.z; ov.w = cv.w + rv.w;
      *(float4*)&out[goff] = ov;
    }
  }
}

// ---------------- launcher ----------------
extern "C" void kernel_launch(void* const* d_in, const int* in_sizes, int n_in,
                              void* d_out, int out_size, void* d_ws, size_t ws_size,
                              hipStream_t stream) {
  const float* x    = (const float*)d_in[0];
  const float* Wq   = (const float*)d_in[1];
  const float* bq   = (const float*)d_in[2];
  const float* Wk   = (const float*)d_in[3];
  const float* bk   = (const float*)d_in[4];
  const float* Wv   = (const float*)d_in[5];
  const float* bv   = (const float*)d_in[6];
  const float* Wo   = (const float*)d_in[7];
  const float* bo   = (const float*)d_in[8];
  const float* ln_g = (const float*)d_in[9];
  const float* ln_b = (const float*)d_in[10];

  char* ws = (char*)d_ws;
  size_t SZ = (size_t)MROWS * DDIM * 2;                    // 100 MB bf16 buffer
  unsigned short* hbuf = (unsigned short*)ws;
  unsigned short* qbuf = (unsigned short*)(ws + SZ);
  char* p = ws + 2 * SZ;
  unsigned short* wf   = (unsigned short*)p;  p += (size_t)1536 * 512 * 2;
  unsigned short* wob  = (unsigned short*)p;  p += (size_t)512 * 512 * 2;
  float* biasf         = (float*)p;           p += 1536 * 4;
  p = (char*)(((uintptr_t)p + 255) & ~(uintptr_t)255);
  unsigned short* part = (unsigned short*)p;  p += (size_t)6144 * PTILE * 2;   // 51 MB
  unsigned short* kvD  = (unsigned short*)p;  p += (size_t)32 * 4096 * 2;
  float* ksum          = (float*)p;           p += 32 * 64 * 4;
  p = (char*)(((uintptr_t)p + 255) & ~(uintptr_t)255);
  unsigned short* Bmat = (unsigned short*)p;  p += (size_t)BATCH * 512 * 512 * 2;  // 2 MB

  wprep<<<(786432 + 262144 + 1536 + 255) / 256, 256, 0, stream>>>(Wq, bq, Wk, bk, Wv, bv, Wo,
                                                                  wf, wob, biasf);
  ln_kernel<<<MROWS / 4, 256, 0, stream>>>(x, ln_g, ln_b, hbuf);
  qkv_gemm<<<MBLK * 12, 256, 0, stream>>>(hbuf, wf, biasf, qbuf, part);
  kv_final<<<dim3(32, (PTILE + 255) / 256), 256, 0, stream>>>(part, kvD, ksum);
  w2_gemm<<<32, 512, 0, stream>>>(kvD, wob, Bmat);
  qscale<<<MROWS / 4, 256, 0, stream>>>(qbuf, ksum);
  ogemm<<<MBLK * 4, 256, 0, stream>>>(qbuf, Bmat, bo, x, (float*)d_out);
}